// Round 4
// baseline (763.119 us; speedup 1.0000x reference)
//
#include <hip/hip_runtime.h>
#include <cstdint>

typedef unsigned short u16;
typedef __attribute__((ext_vector_type(8))) short bf16x8;
typedef __attribute__((ext_vector_type(4))) float f32x4;

#define S_LEN 2048
#define DM    2048
#define NH    16
#define HDIM  128

__device__ __forceinline__ u16 f2bf(float f) {
  union { float f; unsigned u; } v; v.f = f;
  unsigned r = v.u + 0x7fffu + ((v.u >> 16) & 1u);
  return (u16)(r >> 16);
}
__device__ __forceinline__ float bf2f(u16 h) {
  union { unsigned u; float f; } v; v.u = ((unsigned)h) << 16;
  return v.f;
}

typedef __attribute__((address_space(3))) void lds_void_t;
typedef const __attribute__((address_space(1))) void gbl_void_t;
__device__ __forceinline__ void gload_lds16(const void* g, void* l) {
  __builtin_amdgcn_global_load_lds((gbl_void_t*)g, (lds_void_t*)l, 16, 0, 0);
}

// ---------------------------------------------------------------- convert
__global__ void cvt_k(const float* __restrict__ in, u16* __restrict__ out, int n) {
  int n4 = n >> 2;
  int stride = gridDim.x * blockDim.x;
  for (int i = blockIdx.x * blockDim.x + threadIdx.x; i < n4; i += stride) {
    float4 v = ((const float4*)in)[i];
    ushort4 o;
    o.x = f2bf(v.x); o.y = f2bf(v.y); o.z = f2bf(v.z); o.w = f2bf(v.w);
    ((ushort4*)out)[i] = o;
  }
}

// ---------------------------------------------------------------- GEMM  C = A (MxK) * B^T (B given as NxK row-major)
template <typename CT>
__global__ __launch_bounds__(256) void gemm_bt(const u16* __restrict__ A,
                                               const u16* __restrict__ Bm,
                                               CT* __restrict__ C,
                                               int M, int N, int K) {
  __shared__ u16 sA[128 * 32];
  __shared__ u16 sB[128 * 32];
  const int t = threadIdx.x;
  const int lane = t & 63, wid = t >> 6;
  const int r0 = lane & 15, kq = lane >> 4;
  const int wr = wid >> 1, wc = wid & 1;
  const long tile_m = (long)blockIdx.y * 128;
  const long tile_n = (long)blockIdx.x * 128;

  f32x4 acc[4][4];
#pragma unroll
  for (int i = 0; i < 4; ++i)
#pragma unroll
    for (int j = 0; j < 4; ++j)
      acc[i][j] = (f32x4){0.f, 0.f, 0.f, 0.f};

  const int rowA = t >> 2;
  const int colA = (t & 3) * 8;
  const u16* gA = A + (tile_m + rowA) * (long)K + colA;
  const u16* gB = Bm + (tile_n + rowA) * (long)K + colA;
  u16* lA = &sA[(wid * 16) * 32];
  u16* lB = &sB[(wid * 16) * 32];

  for (int k0 = 0; k0 < K; k0 += 32) {
    __syncthreads();
    gload_lds16(gA + k0, lA);
    gload_lds16(gA + k0 + 64 * (long)K, lA + 64 * 32);
    gload_lds16(gB + k0, lB);
    gload_lds16(gB + k0 + 64 * (long)K, lB + 64 * 32);
    __syncthreads();
    bf16x8 af[4], bfr[4];
#pragma unroll
    for (int i = 0; i < 4; ++i)
      af[i] = *(const bf16x8*)&sA[(wr * 64 + i * 16 + r0) * 32 + kq * 8];
#pragma unroll
    for (int i = 0; i < 4; ++i)
      bfr[i] = *(const bf16x8*)&sB[(wc * 64 + i * 16 + r0) * 32 + kq * 8];
#pragma unroll
    for (int i = 0; i < 4; ++i)
#pragma unroll
      for (int j = 0; j < 4; ++j)
        acc[i][j] = __builtin_amdgcn_mfma_f32_16x16x32_bf16(af[i], bfr[j], acc[i][j], 0, 0, 0);
  }

#pragma unroll
  for (int i = 0; i < 4; ++i)
#pragma unroll
    for (int j = 0; j < 4; ++j)
#pragma unroll
      for (int r = 0; r < 4; ++r) {
        long grow = tile_m + wr * 64 + i * 16 + kq * 4 + r;
        long gcol = tile_n + wc * 64 + j * 16 + r0;
        float v = acc[i][j][r];
        if constexpr (sizeof(CT) == 2) C[grow * N + gcol] = (CT)f2bf(v);
        else                           C[grow * N + gcol] = v;
      }
}

// ---------------------------------------------------------------- RoPE + reshape to (B,H,S,HD)
__global__ void rope_k(const u16* __restrict__ qkv, const float* __restrict__ cosT,
                       const float* __restrict__ sinT, u16* __restrict__ qt,
                       u16* __restrict__ kt) {
  int z = blockIdx.y;
  long idx = (long)blockIdx.x * blockDim.x + threadIdx.x;
  int hd2 = (int)(idx & 63);
  int s   = (int)((idx >> 6) & (S_LEN - 1));
  int bh  = (int)(idx >> 17);
  int b = bh >> 4, h = bh & 15;
  const u16* src = qkv + ((long)(b * S_LEN + s)) * 6144 + z * 2048 + h * HDIM + hd2 * 2;
  ushort2 p = *(const ushort2*)src;
  float e = bf2f(p.x), o = bf2f(p.y);
  float c = cosT[s * 64 + hd2], sn = sinT[s * 64 + hd2];
  float oe = e * c - o * sn;
  float oo = e * sn + o * c;
  u16* dst = (z ? kt : qt) + ((long)bh * S_LEN + s) * HDIM + hd2 * 2;
  ushort2 w; w.x = f2bf(oe); w.y = f2bf(oo);
  *(ushort2*)dst = w;
}

// ---------------------------------------------------------------- V transpose -> (B,H,HD,S)
__global__ void vtrans_k(const u16* __restrict__ qkv, u16* __restrict__ vt) {
  __shared__ u16 tile[64][65];
  int bh = blockIdx.z;
  int b = bh >> 4, h = bh & 15;
  int s0 = blockIdx.x * 64, d0 = blockIdx.y * 64;
  int tx = threadIdx.x, ty = threadIdx.y;
#pragma unroll
  for (int i = 0; i < 64; i += 4) {
    int s = s0 + ty + i;
    tile[ty + i][tx] = qkv[((long)(b * S_LEN + s)) * 6144 + 4096 + h * HDIM + d0 + tx];
  }
  __syncthreads();
#pragma unroll
  for (int i = 0; i < 64; i += 4) {
    int d = d0 + ty + i;
    vt[((long)bh * HDIM + d) * S_LEN + s0 + tx] = tile[tx][ty + i];
  }
}

// ---------------------------------------------------------------- flash attention v3 (causal)
// grid (32 qtiles of 64 rows, B*H), 4 waves x 16 q-rows each, KVBLK=64.
// Heavy tiles dispatched first. No launch_bounds min-waves clamp (R3 lesson:
// (256,4) forced 64 VGPR -> scratch spill -> 465us. Plain (256) -> ~128 VGPR).
__global__ __launch_bounds__(256) void flash_k(const u16* __restrict__ qt,
                                               const u16* __restrict__ kt,
                                               const u16* __restrict__ vt,
                                               u16* __restrict__ attn) {
  __shared__ u16 pbuf[4][16 * 64];  // per-wave 16x64 P tile, XOR-swizzled
  const int t = threadIdx.x, lane = t & 63, wid = t >> 6;
  const int r0 = lane & 15, kq = lane >> 4;
  const int bh = blockIdx.y, b = bh >> 4, h = bh & 15;
  const int tile = (gridDim.x - 1) - blockIdx.x;   // heavy-first
  const int q0w = tile * 64 + wid * 16;            // wave's first q row

  const u16* qb = qt + ((long)bh * S_LEN + q0w) * HDIM;
  const u16* kb = kt + (long)bh * S_LEN * HDIM;
  const u16* vb = vt + (long)bh * HDIM * S_LEN;
  u16* pb = &pbuf[wid][0];

  bf16x8 aq[4];
#pragma unroll
  for (int kk = 0; kk < 4; ++kk)
    aq[kk] = *(const bf16x8*)(qb + r0 * HDIM + kk * 32 + kq * 8);

  f32x4 o[8];
  float mrow[4], lrow[4];
#pragma unroll
  for (int dt = 0; dt < 8; ++dt) o[dt] = (f32x4){0.f, 0.f, 0.f, 0.f};
#pragma unroll
  for (int r = 0; r < 4; ++r) { mrow[r] = -1e30f; lrow[r] = 0.f; }

  const float sc = 0.08838834764831845f;  // 1/sqrt(128)
  const int myswz = (r0 & 7) << 3;

  for (int kv0 = 0; kv0 < q0w + 16; kv0 += 64) {
    // mask needed whenever the block's last column exceeds the wave's FIRST row
    const bool need_mask = (kv0 + 63 > q0w);

    f32x4 sacc[4];
#pragma unroll
    for (int kc = 0; kc < 4; ++kc) {
      bf16x8 bk[4];
#pragma unroll
      for (int kk = 0; kk < 4; ++kk)
        bk[kk] = *(const bf16x8*)(kb + (long)(kv0 + kc * 16 + r0) * HDIM + kk * 32 + kq * 8);
      f32x4 a = (f32x4){0.f, 0.f, 0.f, 0.f};
#pragma unroll
      for (int kk = 0; kk < 4; ++kk)
        a = __builtin_amdgcn_mfma_f32_16x16x32_bf16(aq[kk], bk[kk], a, 0, 0, 0);
      sacc[kc] = a;
    }

    float corr[4];
#pragma unroll
    for (int r = 0; r < 4; ++r) {
      int qrow = q0w + kq * 4 + r;
      float s0 = sacc[0][r] * sc, s1 = sacc[1][r] * sc;
      float s2 = sacc[2][r] * sc, s3 = sacc[3][r] * sc;
      if (need_mask) {
        if (kv0 +      r0 > qrow) s0 = -1e30f;
        if (kv0 + 16 + r0 > qrow) s1 = -1e30f;
        if (kv0 + 32 + r0 > qrow) s2 = -1e30f;
        if (kv0 + 48 + r0 > qrow) s3 = -1e30f;
      }
      float mx = fmaxf(fmaxf(s0, s1), fmaxf(s2, s3));
      mx = fmaxf(mx, __shfl_xor(mx, 1));
      mx = fmaxf(mx, __shfl_xor(mx, 2));
      mx = fmaxf(mx, __shfl_xor(mx, 4));
      mx = fmaxf(mx, __shfl_xor(mx, 8));
      float mnew = fmaxf(mrow[r], mx);
      float co = __expf(mrow[r] - mnew);
      mrow[r] = mnew;
      float p0 = __expf(s0 - mnew), p1 = __expf(s1 - mnew);
      float p2 = __expf(s2 - mnew), p3 = __expf(s3 - mnew);
      float rs = (p0 + p1) + (p2 + p3);
      rs += __shfl_xor(rs, 1);
      rs += __shfl_xor(rs, 2);
      rs += __shfl_xor(rs, 4);
      rs += __shfl_xor(rs, 8);
      lrow[r] = lrow[r] * co + rs;
      corr[r] = co;
      int row = kq * 4 + r;
      int swz = (row & 7) << 3;
      u16* prow = pb + row * 64;
      prow[(r0)      ^ swz] = f2bf(p0);
      prow[(16 + r0) ^ swz] = f2bf(p1);
      prow[(32 + r0) ^ swz] = f2bf(p2);
      prow[(48 + r0) ^ swz] = f2bf(p3);
    }
#pragma unroll
    for (int dt = 0; dt < 8; ++dt)
#pragma unroll
      for (int r = 0; r < 4; ++r)
        o[dt][r] *= corr[r];

#pragma unroll
    for (int c = 0; c < 2; ++c) {
      bf16x8 pa = *(const bf16x8*)&pb[(r0 * 64 + c * 32 + kq * 8) ^ myswz];
#pragma unroll
      for (int dt = 0; dt < 8; ++dt) {
        bf16x8 bv = *(const bf16x8*)(vb + (long)(dt * 16 + r0) * S_LEN + kv0 + c * 32 + kq * 8);
        o[dt] = __builtin_amdgcn_mfma_f32_16x16x32_bf16(pa, bv, o[dt], 0, 0, 0);
      }
    }
  }

  float inv[4];
#pragma unroll
  for (int r = 0; r < 4; ++r) inv[r] = 1.0f / lrow[r];
#pragma unroll
  for (int dt = 0; dt < 8; ++dt)
#pragma unroll
    for (int r = 0; r < 4; ++r) {
      int srow = q0w + kq * 4 + r;
      attn[((long)(b * S_LEN + srow)) * DM + h * HDIM + dt * 16 + r0] =
          f2bf(o[dt][r] * inv[r]);
    }
}

// ---------------------------------------------------------------- launch
extern "C" void kernel_launch(void* const* d_in, const int* in_sizes, int n_in,
                              void* d_out, int out_size, void* d_ws, size_t ws_size,
                              hipStream_t stream) {
  (void)in_sizes; (void)n_in; (void)out_size; (void)ws_size;
  const float* x  = (const float*)d_in[0];
  const float* fc = (const float*)d_in[2];
  const float* fs = (const float*)d_in[3];
  const float* wq = (const float*)d_in[5];
  const float* wk = (const float*)d_in[6];
  const float* wv = (const float*)d_in[7];
  const float* wo = (const float*)d_in[8];
  float* out = (float*)d_out;

  u16* xb   = (u16*)d_ws;            // 4096*2048
  u16* wqkv = xb + 8388608;          // 6144*2048
  u16* wob  = wqkv + 12582912;       // 2048*2048
  u16* qkv  = wob + 4194304;         // 4096*6144
  u16* qt   = qkv + 25165824;        // 32*2048*128
  u16* kt   = qt + 8388608;
  u16* vt   = kt + 8388608;
  u16* attn = qkv;                   // alias: qkv dead after rope/vtrans

  cvt_k<<<4096, 256, 0, stream>>>(x, xb, 8388608);
  cvt_k<<<2048, 256, 0, stream>>>(wq, wqkv, 4194304);
  cvt_k<<<2048, 256, 0, stream>>>(wk, wqkv + 4194304, 4194304);
  cvt_k<<<2048, 256, 0, stream>>>(wv, wqkv + 8388608, 4194304);
  cvt_k<<<2048, 256, 0, stream>>>(wo, wob, 4194304);

  gemm_bt<u16><<<dim3(48, 32), 256, 0, stream>>>(xb, wqkv, qkv, 4096, 6144, 2048);

  rope_k<<<dim3(16384, 2), 256, 0, stream>>>(qkv, fc, fs, qt, kt);
  vtrans_k<<<dim3(32, 2, 32), dim3(64, 4), 0, stream>>>(qkv, vt);

  flash_k<<<dim3(32, 32), 256, 0, stream>>>(qt, kt, vt, attn);

  gemm_bt<float><<<dim3(16, 32), 256, 0, stream>>>(attn, wob, out, 4096, 2048, 2048);
}

// Round 5
// 403.412 us; speedup vs baseline: 1.8917x; 1.8917x over previous
//
#include <hip/hip_runtime.h>
#include <cstdint>

typedef unsigned short u16;
typedef __attribute__((ext_vector_type(8))) short bf16x8;
typedef __attribute__((ext_vector_type(4))) float f32x4;

#define S_LEN 2048
#define DM    2048
#define NH    16
#define HDIM  128

__device__ __forceinline__ u16 f2bf(float f) {
  union { float f; unsigned u; } v; v.f = f;
  unsigned r = v.u + 0x7fffu + ((v.u >> 16) & 1u);
  return (u16)(r >> 16);
}
__device__ __forceinline__ float bf2f(u16 h) {
  union { unsigned u; float f; } v; v.u = ((unsigned)h) << 16;
  return v.f;
}

typedef __attribute__((address_space(3))) void lds_void_t;
typedef const __attribute__((address_space(1))) void gbl_void_t;
__device__ __forceinline__ void gload_lds16(const void* g, void* l) {
  __builtin_amdgcn_global_load_lds((gbl_void_t*)g, (lds_void_t*)l, 16, 0, 0);
}

// ---------------------------------------------------------------- convert
__global__ void cvt_k(const float* __restrict__ in, u16* __restrict__ out, int n) {
  int n4 = n >> 2;
  int stride = gridDim.x * blockDim.x;
  for (int i = blockIdx.x * blockDim.x + threadIdx.x; i < n4; i += stride) {
    float4 v = ((const float4*)in)[i];
    ushort4 o;
    o.x = f2bf(v.x); o.y = f2bf(v.y); o.z = f2bf(v.z); o.w = f2bf(v.w);
    ((ushort4*)out)[i] = o;
  }
}

// ---------------------------------------------------------------- GEMM  C = A (MxK) * B^T (B given as NxK row-major)
template <typename CT>
__global__ __launch_bounds__(256) void gemm_bt(const u16* __restrict__ A,
                                               const u16* __restrict__ Bm,
                                               CT* __restrict__ C,
                                               int M, int N, int K) {
  __shared__ u16 sA[128 * 32];
  __shared__ u16 sB[128 * 32];
  const int t = threadIdx.x;
  const int lane = t & 63, wid = t >> 6;
  const int r0 = lane & 15, kq = lane >> 4;
  const int wr = wid >> 1, wc = wid & 1;
  const long tile_m = (long)blockIdx.y * 128;
  const long tile_n = (long)blockIdx.x * 128;

  f32x4 acc[4][4];
#pragma unroll
  for (int i = 0; i < 4; ++i)
#pragma unroll
    for (int j = 0; j < 4; ++j)
      acc[i][j] = (f32x4){0.f, 0.f, 0.f, 0.f};

  const int rowA = t >> 2;
  const int colA = (t & 3) * 8;
  const u16* gA = A + (tile_m + rowA) * (long)K + colA;
  const u16* gB = Bm + (tile_n + rowA) * (long)K + colA;
  u16* lA = &sA[(wid * 16) * 32];
  u16* lB = &sB[(wid * 16) * 32];

  for (int k0 = 0; k0 < K; k0 += 32) {
    __syncthreads();
    gload_lds16(gA + k0, lA);
    gload_lds16(gA + k0 + 64 * (long)K, lA + 64 * 32);
    gload_lds16(gB + k0, lB);
    gload_lds16(gB + k0 + 64 * (long)K, lB + 64 * 32);
    __syncthreads();
    bf16x8 af[4], bfr[4];
#pragma unroll
    for (int i = 0; i < 4; ++i)
      af[i] = *(const bf16x8*)&sA[(wr * 64 + i * 16 + r0) * 32 + kq * 8];
#pragma unroll
    for (int i = 0; i < 4; ++i)
      bfr[i] = *(const bf16x8*)&sB[(wc * 64 + i * 16 + r0) * 32 + kq * 8];
#pragma unroll
    for (int i = 0; i < 4; ++i)
#pragma unroll
      for (int j = 0; j < 4; ++j)
        acc[i][j] = __builtin_amdgcn_mfma_f32_16x16x32_bf16(af[i], bfr[j], acc[i][j], 0, 0, 0);
  }

#pragma unroll
  for (int i = 0; i < 4; ++i)
#pragma unroll
    for (int j = 0; j < 4; ++j)
#pragma unroll
      for (int r = 0; r < 4; ++r) {
        long grow = tile_m + wr * 64 + i * 16 + kq * 4 + r;
        long gcol = tile_n + wc * 64 + j * 16 + r0;
        float v = acc[i][j][r];
        if constexpr (sizeof(CT) == 2) C[grow * N + gcol] = (CT)f2bf(v);
        else                           C[grow * N + gcol] = v;
      }
}

// ---------------------------------------------------------------- RoPE + reshape to (B,H,S,HD)
// q output (z==0) is pre-scaled by 1/sqrt(HD): scaling commutes with rotation.
__global__ void rope_k(const u16* __restrict__ qkv, const float* __restrict__ cosT,
                       const float* __restrict__ sinT, u16* __restrict__ qt,
                       u16* __restrict__ kt) {
  int z = blockIdx.y;
  long idx = (long)blockIdx.x * blockDim.x + threadIdx.x;
  int hd2 = (int)(idx & 63);
  int s   = (int)((idx >> 6) & (S_LEN - 1));
  int bh  = (int)(idx >> 17);
  int b = bh >> 4, h = bh & 15;
  const u16* src = qkv + ((long)(b * S_LEN + s)) * 6144 + z * 2048 + h * HDIM + hd2 * 2;
  ushort2 p = *(const ushort2*)src;
  float e = bf2f(p.x), o = bf2f(p.y);
  float c = cosT[s * 64 + hd2], sn = sinT[s * 64 + hd2];
  float oe = e * c - o * sn;
  float oo = e * sn + o * c;
  if (z == 0) {
    const float sc = 0.08838834764831845f;  // 1/sqrt(128)
    oe *= sc; oo *= sc;
  }
  u16* dst = (z ? kt : qt) + ((long)bh * S_LEN + s) * HDIM + hd2 * 2;
  ushort2 w; w.x = f2bf(oe); w.y = f2bf(oo);
  *(ushort2*)dst = w;
}

// ---------------------------------------------------------------- V transpose -> (B,H,HD,S)
__global__ void vtrans_k(const u16* __restrict__ qkv, u16* __restrict__ vt) {
  __shared__ u16 tile[64][65];
  int bh = blockIdx.z;
  int b = bh >> 4, h = bh & 15;
  int s0 = blockIdx.x * 64, d0 = blockIdx.y * 64;
  int tx = threadIdx.x, ty = threadIdx.y;
#pragma unroll
  for (int i = 0; i < 64; i += 4) {
    int s = s0 + ty + i;
    tile[ty + i][tx] = qkv[((long)(b * S_LEN + s)) * 6144 + 4096 + h * HDIM + d0 + tx];
  }
  __syncthreads();
#pragma unroll
  for (int i = 0; i < 64; i += 4) {
    int d = d0 + ty + i;
    vt[((long)bh * HDIM + d) * S_LEN + s0 + tx] = tile[tx][ty + i];
  }
}

// ---------------------------------------------------------------- flash attention v4 (causal)
// Swapped QK^T (mfma(K,Q)): P's kv-axis lands lane-local -> row reduce is
// 7 in-lane fmax + 2 shfl_xor instead of 8 serial shfl per row (64->8 per step).
// Defer-max (THR=8) skips the O-rescale + corr shfls unless max grows.
// 2 waves/block x 32 q-rows, KVBLK=32, grid (bh=32, tile=32) heavy-first.
__global__ __launch_bounds__(128, 2) void flash_k(const u16* __restrict__ qt,
                                                  const u16* __restrict__ kt,
                                                  const u16* __restrict__ vt,
                                                  u16* __restrict__ attn) {
  __shared__ u16 pbuf[2][32 * 32];  // per-wave 32q x 32kv P tile
  const int t = threadIdx.x, lane = t & 63, wid = t >> 6;
  const int r0 = lane & 15, kq = lane >> 4;
  const int bh = blockIdx.x, b = bh >> 4, h = bh & 15;
  const int tile = (gridDim.y - 1) - blockIdx.y;   // heavy-first
  const int q0w = tile * 64 + wid * 32;            // wave's first q row
  const int crow = kq * 4;                         // C-layout row base

  const u16* qb = qt + ((long)bh * S_LEN + q0w) * HDIM;
  const u16* kb = kt + (long)bh * S_LEN * HDIM;
  const u16* vb = vt + (long)bh * HDIM * S_LEN;
  u16* pb = &pbuf[wid][0];

  bf16x8 aq[2][4];
#pragma unroll
  for (int qc = 0; qc < 2; ++qc)
#pragma unroll
    for (int kk = 0; kk < 4; ++kk)
      aq[qc][kk] = *(const bf16x8*)(qb + (qc * 16 + r0) * HDIM + kk * 32 + kq * 8);

  f32x4 o[2][8];
  float mrow[2] = {-1e30f, -1e30f}, lrow[2] = {0.f, 0.f};
#pragma unroll
  for (int qc = 0; qc < 2; ++qc)
#pragma unroll
    for (int dt = 0; dt < 8; ++dt) o[qc][dt] = (f32x4){0.f, 0.f, 0.f, 0.f};

  for (int kv0 = 0; kv0 <= q0w; kv0 += 32) {
    const bool diag = (kv0 == q0w);

    // --- QK^T, swapped operands: sacc[kc][qc], lane holds P[kv=crow+r][q=r0]
    f32x4 sacc[2][2];
    __builtin_amdgcn_s_setprio(1);
#pragma unroll
    for (int kc = 0; kc < 2; ++kc) {
      bf16x8 bk[4];
#pragma unroll
      for (int kk = 0; kk < 4; ++kk)
        bk[kk] = *(const bf16x8*)(kb + (long)(kv0 + kc * 16 + r0) * HDIM + kk * 32 + kq * 8);
      f32x4 a0 = (f32x4){0.f, 0.f, 0.f, 0.f};
      f32x4 a1 = (f32x4){0.f, 0.f, 0.f, 0.f};
#pragma unroll
      for (int kk = 0; kk < 4; ++kk) {
        a0 = __builtin_amdgcn_mfma_f32_16x16x32_bf16(bk[kk], aq[0][kk], a0, 0, 0, 0);
        a1 = __builtin_amdgcn_mfma_f32_16x16x32_bf16(bk[kk], aq[1][kk], a1, 0, 0, 0);
      }
      sacc[kc][0] = a0; sacc[kc][1] = a1;
    }
    __builtin_amdgcn_s_setprio(0);

    // --- softmax (kv lane-local; q = qc*16 + r0)
#pragma unroll
    for (int qc = 0; qc < 2; ++qc) {
      float s[2][4];
#pragma unroll
      for (int kc = 0; kc < 2; ++kc)
#pragma unroll
        for (int r = 0; r < 4; ++r) {
          float v = sacc[kc][qc][r];
          if (diag && (kc * 16 + crow + r > qc * 16 + r0)) v = -1e30f;
          s[kc][r] = v;
        }
      float pm = fmaxf(fmaxf(fmaxf(s[0][0], s[0][1]), fmaxf(s[0][2], s[0][3])),
                       fmaxf(fmaxf(s[1][0], s[1][1]), fmaxf(s[1][2], s[1][3])));
      pm = fmaxf(pm, __shfl_xor(pm, 16));
      pm = fmaxf(pm, __shfl_xor(pm, 32));
      if (!__all(pm - mrow[qc] <= 8.0f)) {   // defer-max: rescale rarely
        float mnew = fmaxf(mrow[qc], pm);
        float co = __expf(mrow[qc] - mnew);
        mrow[qc] = mnew;
        lrow[qc] *= co;
        float cod[4];
#pragma unroll
        for (int r = 0; r < 4; ++r)
          cod[r] = __shfl(co, (lane & 48) | (crow + r));
#pragma unroll
        for (int dt = 0; dt < 8; ++dt)
#pragma unroll
          for (int r = 0; r < 4; ++r)
            o[qc][dt][r] *= cod[r];
      }
      float p[2][4];
      float rs = 0.f;
#pragma unroll
      for (int kc = 0; kc < 2; ++kc)
#pragma unroll
        for (int r = 0; r < 4; ++r) {
          p[kc][r] = __expf(s[kc][r] - mrow[qc]);
          rs += p[kc][r];
        }
      rs += __shfl_xor(rs, 16);
      rs += __shfl_xor(rs, 32);
      lrow[qc] += rs;
#pragma unroll
      for (int kc = 0; kc < 2; ++kc) {
        ushort4 pk;
        pk.x = f2bf(p[kc][0]); pk.y = f2bf(p[kc][1]);
        pk.z = f2bf(p[kc][2]); pk.w = f2bf(p[kc][3]);
        *(ushort4*)(pb + (qc * 16 + r0) * 32 + kc * 16 + crow) = pk;
      }
    }

    // --- PV: pa is A-frag (q rows), bv is B-frag (d cols, kv k-dim)
    bf16x8 pa0 = *(const bf16x8*)(pb + r0 * 32 + kq * 8);
    bf16x8 pa1 = *(const bf16x8*)(pb + (16 + r0) * 32 + kq * 8);
    __builtin_amdgcn_s_setprio(1);
#pragma unroll
    for (int dt = 0; dt < 8; ++dt) {
      bf16x8 bv = *(const bf16x8*)(vb + (long)(dt * 16 + r0) * S_LEN + kv0 + kq * 8);
      o[0][dt] = __builtin_amdgcn_mfma_f32_16x16x32_bf16(pa0, bv, o[0][dt], 0, 0, 0);
      o[1][dt] = __builtin_amdgcn_mfma_f32_16x16x32_bf16(pa1, bv, o[1][dt], 0, 0, 0);
    }
    __builtin_amdgcn_s_setprio(0);
  }

  // --- epilogue: redistribute l to C-layout rows, normalize, store
#pragma unroll
  for (int qc = 0; qc < 2; ++qc) {
    float linv[4];
#pragma unroll
    for (int r = 0; r < 4; ++r)
      linv[r] = 1.0f / __shfl(lrow[qc], (lane & 48) | (crow + r));
#pragma unroll
    for (int dt = 0; dt < 8; ++dt)
#pragma unroll
      for (int r = 0; r < 4; ++r) {
        int srow = q0w + qc * 16 + crow + r;
        attn[((long)(b * S_LEN + srow)) * DM + h * HDIM + dt * 16 + r0] =
            f2bf(o[qc][dt][r] * linv[r]);
      }
  }
}

// ---------------------------------------------------------------- launch
extern "C" void kernel_launch(void* const* d_in, const int* in_sizes, int n_in,
                              void* d_out, int out_size, void* d_ws, size_t ws_size,
                              hipStream_t stream) {
  (void)in_sizes; (void)n_in; (void)out_size; (void)ws_size;
  const float* x  = (const float*)d_in[0];
  const float* fc = (const float*)d_in[2];
  const float* fs = (const float*)d_in[3];
  const float* wq = (const float*)d_in[5];
  const float* wk = (const float*)d_in[6];
  const float* wv = (const float*)d_in[7];
  const float* wo = (const float*)d_in[8];
  float* out = (float*)d_out;

  u16* xb   = (u16*)d_ws;            // 4096*2048
  u16* wqkv = xb + 8388608;          // 6144*2048
  u16* wob  = wqkv + 12582912;       // 2048*2048
  u16* qkv  = wob + 4194304;         // 4096*6144
  u16* qt   = qkv + 25165824;        // 32*2048*128
  u16* kt   = qt + 8388608;
  u16* vt   = kt + 8388608;
  u16* attn = qkv;                   // alias: qkv dead after rope/vtrans

  cvt_k<<<4096, 256, 0, stream>>>(x, xb, 8388608);
  cvt_k<<<2048, 256, 0, stream>>>(wq, wqkv, 4194304);
  cvt_k<<<2048, 256, 0, stream>>>(wk, wqkv + 4194304, 4194304);
  cvt_k<<<2048, 256, 0, stream>>>(wv, wqkv + 8388608, 4194304);
  cvt_k<<<2048, 256, 0, stream>>>(wo, wob, 4194304);

  gemm_bt<u16><<<dim3(48, 32), 256, 0, stream>>>(xb, wqkv, qkv, 4096, 6144, 2048);

  rope_k<<<dim3(16384, 2), 256, 0, stream>>>(qkv, fc, fs, qt, kt);
  vtrans_k<<<dim3(32, 2, 32), dim3(64, 4), 0, stream>>>(qkv, vt);

  // grid: x = bh (same-bh blocks pack onto one XCD L2), y = q-tile (heavy-first)
  flash_k<<<dim3(32, 32), 128, 0, stream>>>(qt, kt, vt, attn);

  gemm_bt<float><<<dim3(16, 32), 256, 0, stream>>>(attn, wob, out, 4096, 2048, 2048);
}

// Round 6
// 386.646 us; speedup vs baseline: 1.9737x; 1.0434x over previous
//
#include <hip/hip_runtime.h>
#include <cstdint>

typedef unsigned short u16;
typedef __attribute__((ext_vector_type(8))) short bf16x8;
typedef __attribute__((ext_vector_type(4))) float f32x4;

#define S_LEN 2048
#define DM    2048
#define NH    16
#define HDIM  128

__device__ __forceinline__ u16 f2bf(float f) {
  union { float f; unsigned u; } v; v.f = f;
  unsigned r = v.u + 0x7fffu + ((v.u >> 16) & 1u);
  return (u16)(r >> 16);
}
__device__ __forceinline__ float bf2f(u16 h) {
  union { unsigned u; float f; } v; v.u = ((unsigned)h) << 16;
  return v.f;
}

typedef __attribute__((address_space(3))) void lds_void_t;
typedef const __attribute__((address_space(1))) void gbl_void_t;
__device__ __forceinline__ void gload_lds16(const void* g, void* l) {
  __builtin_amdgcn_global_load_lds((gbl_void_t*)g, (lds_void_t*)l, 16, 0, 0);
}

// ---------------------------------------------------------------- convert
__global__ void cvt_k(const float* __restrict__ in, u16* __restrict__ out, int n) {
  int n4 = n >> 2;
  int stride = gridDim.x * blockDim.x;
  for (int i = blockIdx.x * blockDim.x + threadIdx.x; i < n4; i += stride) {
    float4 v = ((const float4*)in)[i];
    ushort4 o;
    o.x = f2bf(v.x); o.y = f2bf(v.y); o.z = f2bf(v.z); o.w = f2bf(v.w);
    ((ushort4*)out)[i] = o;
  }
}

// ---------------------------------------------------------------- GEMM  C = A (MxK) * B^T (B given as NxK row-major)
template <typename CT>
__global__ __launch_bounds__(256) void gemm_bt(const u16* __restrict__ A,
                                               const u16* __restrict__ Bm,
                                               CT* __restrict__ C,
                                               int M, int N, int K) {
  __shared__ u16 sA[128 * 32];
  __shared__ u16 sB[128 * 32];
  const int t = threadIdx.x;
  const int lane = t & 63, wid = t >> 6;
  const int r0 = lane & 15, kq = lane >> 4;
  const int wr = wid >> 1, wc = wid & 1;
  const long tile_m = (long)blockIdx.y * 128;
  const long tile_n = (long)blockIdx.x * 128;

  f32x4 acc[4][4];
#pragma unroll
  for (int i = 0; i < 4; ++i)
#pragma unroll
    for (int j = 0; j < 4; ++j)
      acc[i][j] = (f32x4){0.f, 0.f, 0.f, 0.f};

  const int rowA = t >> 2;
  const int colA = (t & 3) * 8;
  const u16* gA = A + (tile_m + rowA) * (long)K + colA;
  const u16* gB = Bm + (tile_n + rowA) * (long)K + colA;
  u16* lA = &sA[(wid * 16) * 32];
  u16* lB = &sB[(wid * 16) * 32];

  for (int k0 = 0; k0 < K; k0 += 32) {
    __syncthreads();
    gload_lds16(gA + k0, lA);
    gload_lds16(gA + k0 + 64 * (long)K, lA + 64 * 32);
    gload_lds16(gB + k0, lB);
    gload_lds16(gB + k0 + 64 * (long)K, lB + 64 * 32);
    __syncthreads();
    bf16x8 af[4], bfr[4];
#pragma unroll
    for (int i = 0; i < 4; ++i)
      af[i] = *(const bf16x8*)&sA[(wr * 64 + i * 16 + r0) * 32 + kq * 8];
#pragma unroll
    for (int i = 0; i < 4; ++i)
      bfr[i] = *(const bf16x8*)&sB[(wc * 64 + i * 16 + r0) * 32 + kq * 8];
#pragma unroll
    for (int i = 0; i < 4; ++i)
#pragma unroll
      for (int j = 0; j < 4; ++j)
        acc[i][j] = __builtin_amdgcn_mfma_f32_16x16x32_bf16(af[i], bfr[j], acc[i][j], 0, 0, 0);
  }

#pragma unroll
  for (int i = 0; i < 4; ++i)
#pragma unroll
    for (int j = 0; j < 4; ++j)
#pragma unroll
      for (int r = 0; r < 4; ++r) {
        long grow = tile_m + wr * 64 + i * 16 + kq * 4 + r;
        long gcol = tile_n + wc * 64 + j * 16 + r0;
        float v = acc[i][j][r];
        if constexpr (sizeof(CT) == 2) C[grow * N + gcol] = (CT)f2bf(v);
        else                           C[grow * N + gcol] = v;
      }
}

// ---------------------------------------------------------------- RoPE + reshape to (B,H,S,HD)
// q output (z==0) is pre-scaled by 1/sqrt(HD): scaling commutes with rotation.
__global__ void rope_k(const u16* __restrict__ qkv, const float* __restrict__ cosT,
                       const float* __restrict__ sinT, u16* __restrict__ qt,
                       u16* __restrict__ kt) {
  int z = blockIdx.y;
  long idx = (long)blockIdx.x * blockDim.x + threadIdx.x;
  int hd2 = (int)(idx & 63);
  int s   = (int)((idx >> 6) & (S_LEN - 1));
  int bh  = (int)(idx >> 17);
  int b = bh >> 4, h = bh & 15;
  const u16* src = qkv + ((long)(b * S_LEN + s)) * 6144 + z * 2048 + h * HDIM + hd2 * 2;
  ushort2 p = *(const ushort2*)src;
  float e = bf2f(p.x), o = bf2f(p.y);
  float c = cosT[s * 64 + hd2], sn = sinT[s * 64 + hd2];
  float oe = e * c - o * sn;
  float oo = e * sn + o * c;
  if (z == 0) {
    const float sc = 0.08838834764831845f;  // 1/sqrt(128)
    oe *= sc; oo *= sc;
  }
  u16* dst = (z ? kt : qt) + ((long)bh * S_LEN + s) * HDIM + hd2 * 2;
  ushort2 w; w.x = f2bf(oe); w.y = f2bf(oo);
  *(ushort2*)dst = w;
}

// ---------------------------------------------------------------- V transpose -> (B,H,HD,S)
__global__ void vtrans_k(const u16* __restrict__ qkv, u16* __restrict__ vt) {
  __shared__ u16 tile[64][65];
  int bh = blockIdx.z;
  int b = bh >> 4, h = bh & 15;
  int s0 = blockIdx.x * 64, d0 = blockIdx.y * 64;
  int tx = threadIdx.x, ty = threadIdx.y;
#pragma unroll
  for (int i = 0; i < 64; i += 4) {
    int s = s0 + ty + i;
    tile[ty + i][tx] = qkv[((long)(b * S_LEN + s)) * 6144 + 4096 + h * HDIM + d0 + tx];
  }
  __syncthreads();
#pragma unroll
  for (int i = 0; i < 64; i += 4) {
    int d = d0 + ty + i;
    vt[((long)bh * HDIM + d) * S_LEN + s0 + tx] = tile[tx][ty + i];
  }
}

// ---------------------------------------------------------------- flash attention v5 (causal)
// v4 + (a) pbuf stride 40 u16: bank starts spread over 8 multiples of 4
// (stride-32 had row*16%32 in {0,16} -> 8-way conflict, 7.99M counter);
// (b) K double-buffer prefetch (two NAMED buffers, rule #20): next K tile's
// loads issue right after QK MFMAs, softmax VALU chain hides the latency.
__global__ __launch_bounds__(128, 2) void flash_k(const u16* __restrict__ qt,
                                                  const u16* __restrict__ kt,
                                                  const u16* __restrict__ vt,
                                                  u16* __restrict__ attn) {
  constexpr int PS = 40;              // pbuf row stride in u16 (80B, 16B-aligned)
  __shared__ u16 pbuf[2][32 * PS];
  const int t = threadIdx.x, lane = t & 63, wid = t >> 6;
  const int r0 = lane & 15, kq = lane >> 4;
  const int bh = blockIdx.x, b = bh >> 4, h = bh & 15;
  const int tile = (gridDim.y - 1) - blockIdx.y;   // heavy-first
  const int q0w = tile * 64 + wid * 32;            // wave's first q row
  const int crow = kq * 4;                         // C-layout row base

  const u16* qb = qt + ((long)bh * S_LEN + q0w) * HDIM;
  const u16* kb = kt + (long)bh * S_LEN * HDIM;
  const u16* vb = vt + (long)bh * HDIM * S_LEN;
  u16* pb = &pbuf[wid][0];

  bf16x8 aq[2][4];
#pragma unroll
  for (int qc = 0; qc < 2; ++qc)
#pragma unroll
    for (int kk = 0; kk < 4; ++kk)
      aq[qc][kk] = *(const bf16x8*)(qb + (qc * 16 + r0) * HDIM + kk * 32 + kq * 8);

  f32x4 o[2][8];
  float mrow[2] = {-1e30f, -1e30f}, lrow[2] = {0.f, 0.f};
#pragma unroll
  for (int qc = 0; qc < 2; ++qc)
#pragma unroll
    for (int dt = 0; dt < 8; ++dt) o[qc][dt] = (f32x4){0.f, 0.f, 0.f, 0.f};

  bf16x8 bkA[2][4], bkB[2][4];

  auto loadK = [&](bf16x8 (&dst)[2][4], int kv) {
#pragma unroll
    for (int kc = 0; kc < 2; ++kc)
#pragma unroll
      for (int kk = 0; kk < 4; ++kk)
        dst[kc][kk] = *(const bf16x8*)(kb + (long)(kv + kc * 16 + r0) * HDIM + kk * 32 + kq * 8);
  };

  auto step = [&](bf16x8 (&kf)[2][4], bf16x8 (&kfn)[2][4], int kv0) {
    const bool diag = (kv0 == q0w);

    // --- QK^T, swapped operands: lane holds P[kv=kc*16+crow+r][q=qc*16+r0]
    f32x4 sacc[2][2];
    __builtin_amdgcn_s_setprio(1);
#pragma unroll
    for (int kc = 0; kc < 2; ++kc) {
      f32x4 a0 = (f32x4){0.f, 0.f, 0.f, 0.f};
      f32x4 a1 = (f32x4){0.f, 0.f, 0.f, 0.f};
#pragma unroll
      for (int kk = 0; kk < 4; ++kk) {
        a0 = __builtin_amdgcn_mfma_f32_16x16x32_bf16(kf[kc][kk], aq[0][kk], a0, 0, 0, 0);
        a1 = __builtin_amdgcn_mfma_f32_16x16x32_bf16(kf[kc][kk], aq[1][kk], a1, 0, 0, 0);
      }
      sacc[kc][0] = a0; sacc[kc][1] = a1;
    }
    __builtin_amdgcn_s_setprio(0);

    // prefetch next K tile; softmax below hides the latency
    if (kv0 + 32 <= q0w) loadK(kfn, kv0 + 32);

    // --- softmax (kv lane-local; q = qc*16 + r0)
#pragma unroll
    for (int qc = 0; qc < 2; ++qc) {
      float s[2][4];
#pragma unroll
      for (int kc = 0; kc < 2; ++kc)
#pragma unroll
        for (int r = 0; r < 4; ++r) {
          float v = sacc[kc][qc][r];
          if (diag && (kc * 16 + crow + r > qc * 16 + r0)) v = -1e30f;
          s[kc][r] = v;
        }
      float pm = fmaxf(fmaxf(fmaxf(s[0][0], s[0][1]), fmaxf(s[0][2], s[0][3])),
                       fmaxf(fmaxf(s[1][0], s[1][1]), fmaxf(s[1][2], s[1][3])));
      pm = fmaxf(pm, __shfl_xor(pm, 16));
      pm = fmaxf(pm, __shfl_xor(pm, 32));
      if (!__all(pm - mrow[qc] <= 8.0f)) {   // defer-max: rescale rarely
        float mnew = fmaxf(mrow[qc], pm);
        float co = __expf(mrow[qc] - mnew);
        mrow[qc] = mnew;
        lrow[qc] *= co;
        float cod[4];
#pragma unroll
        for (int r = 0; r < 4; ++r)
          cod[r] = __shfl(co, (lane & 48) | (crow + r));
#pragma unroll
        for (int dt = 0; dt < 8; ++dt)
#pragma unroll
          for (int r = 0; r < 4; ++r)
            o[qc][dt][r] *= cod[r];
      }
      float p[2][4];
      float rs = 0.f;
#pragma unroll
      for (int kc = 0; kc < 2; ++kc)
#pragma unroll
        for (int r = 0; r < 4; ++r) {
          p[kc][r] = __expf(s[kc][r] - mrow[qc]);
          rs += p[kc][r];
        }
      rs += __shfl_xor(rs, 16);
      rs += __shfl_xor(rs, 32);
      lrow[qc] += rs;
#pragma unroll
      for (int kc = 0; kc < 2; ++kc) {
        ushort4 pk;
        pk.x = f2bf(p[kc][0]); pk.y = f2bf(p[kc][1]);
        pk.z = f2bf(p[kc][2]); pk.w = f2bf(p[kc][3]);
        *(ushort4*)(pb + (qc * 16 + r0) * PS + kc * 16 + crow) = pk;
      }
    }

    // --- PV: batch all V loads, then MFMA cluster
    bf16x8 bv[8];
#pragma unroll
    for (int dt = 0; dt < 8; ++dt)
      bv[dt] = *(const bf16x8*)(vb + (long)(dt * 16 + r0) * S_LEN + kv0 + kq * 8);
    bf16x8 pa0 = *(const bf16x8*)(pb + r0 * PS + kq * 8);
    bf16x8 pa1 = *(const bf16x8*)(pb + (16 + r0) * PS + kq * 8);
    __builtin_amdgcn_s_setprio(1);
#pragma unroll
    for (int dt = 0; dt < 8; ++dt) {
      o[0][dt] = __builtin_amdgcn_mfma_f32_16x16x32_bf16(pa0, bv[dt], o[0][dt], 0, 0, 0);
      o[1][dt] = __builtin_amdgcn_mfma_f32_16x16x32_bf16(pa1, bv[dt], o[1][dt], 0, 0, 0);
    }
    __builtin_amdgcn_s_setprio(0);
  };

  loadK(bkA, 0);
  int kv0 = 0;
  for (;;) {
    step(bkA, bkB, kv0); kv0 += 32; if (kv0 > q0w) break;
    step(bkB, bkA, kv0); kv0 += 32; if (kv0 > q0w) break;
  }

  // --- epilogue: redistribute l to C-layout rows, normalize, store
#pragma unroll
  for (int qc = 0; qc < 2; ++qc) {
    float linv[4];
#pragma unroll
    for (int r = 0; r < 4; ++r)
      linv[r] = 1.0f / __shfl(lrow[qc], (lane & 48) | (crow + r));
#pragma unroll
    for (int dt = 0; dt < 8; ++dt)
#pragma unroll
      for (int r = 0; r < 4; ++r) {
        int srow = q0w + qc * 16 + crow + r;
        attn[((long)(b * S_LEN + srow)) * DM + h * HDIM + dt * 16 + r0] =
            f2bf(o[qc][dt][r] * linv[r]);
      }
  }
}

// ---------------------------------------------------------------- launch
extern "C" void kernel_launch(void* const* d_in, const int* in_sizes, int n_in,
                              void* d_out, int out_size, void* d_ws, size_t ws_size,
                              hipStream_t stream) {
  (void)in_sizes; (void)n_in; (void)out_size; (void)ws_size;
  const float* x  = (const float*)d_in[0];
  const float* fc = (const float*)d_in[2];
  const float* fs = (const float*)d_in[3];
  const float* wq = (const float*)d_in[5];
  const float* wk = (const float*)d_in[6];
  const float* wv = (const float*)d_in[7];
  const float* wo = (const float*)d_in[8];
  float* out = (float*)d_out;

  u16* xb   = (u16*)d_ws;            // 4096*2048
  u16* wqkv = xb + 8388608;          // 6144*2048
  u16* wob  = wqkv + 12582912;       // 2048*2048
  u16* qkv  = wob + 4194304;         // 4096*6144
  u16* qt   = qkv + 25165824;        // 32*2048*128
  u16* kt   = qt + 8388608;
  u16* vt   = kt + 8388608;
  u16* attn = qkv;                   // alias: qkv dead after rope/vtrans

  cvt_k<<<4096, 256, 0, stream>>>(x, xb, 8388608);
  cvt_k<<<2048, 256, 0, stream>>>(wq, wqkv, 4194304);
  cvt_k<<<2048, 256, 0, stream>>>(wk, wqkv + 4194304, 4194304);
  cvt_k<<<2048, 256, 0, stream>>>(wv, wqkv + 8388608, 4194304);
  cvt_k<<<2048, 256, 0, stream>>>(wo, wob, 4194304);

  gemm_bt<u16><<<dim3(48, 32), 256, 0, stream>>>(xb, wqkv, qkv, 4096, 6144, 2048);

  rope_k<<<dim3(16384, 2), 256, 0, stream>>>(qkv, fc, fs, qt, kt);
  vtrans_k<<<dim3(32, 2, 32), dim3(64, 4), 0, stream>>>(qkv, vt);

  // grid: x = bh (same-bh blocks pack onto one XCD L2), y = q-tile (heavy-first)
  flash_k<<<dim3(32, 32), 128, 0, stream>>>(qt, kt, vt, attn);

  gemm_bt<float><<<dim3(16, 32), 256, 0, stream>>>(attn, wob, out, 4096, 2048, 2048);
}

// Round 7
// 383.173 us; speedup vs baseline: 1.9916x; 1.0091x over previous
//
#include <hip/hip_runtime.h>
#include <cstdint>

typedef unsigned short u16;
typedef __attribute__((ext_vector_type(8))) short bf16x8;
typedef __attribute__((ext_vector_type(4))) float f32x4;

#define S_LEN 2048
#define DM    2048
#define NH    16
#define HDIM  128

__device__ __forceinline__ u16 f2bf(float f) {
  union { float f; unsigned u; } v; v.f = f;
  unsigned r = v.u + 0x7fffu + ((v.u >> 16) & 1u);
  return (u16)(r >> 16);
}
__device__ __forceinline__ float bf2f(u16 h) {
  union { unsigned u; float f; } v; v.u = ((unsigned)h) << 16;
  return v.f;
}

typedef __attribute__((address_space(3))) void lds_void_t;
typedef const __attribute__((address_space(1))) void gbl_void_t;
__device__ __forceinline__ void gload_lds16(const void* g, void* l) {
  __builtin_amdgcn_global_load_lds((gbl_void_t*)g, (lds_void_t*)l, 16, 0, 0);
}

#define VMCNTN(nn) asm volatile("s_waitcnt vmcnt(%0)" :: "n"(nn) : "memory")

// ---------------------------------------------------------------- convert
__global__ void cvt_k(const float* __restrict__ in, u16* __restrict__ out, int n) {
  int n4 = n >> 2;
  int stride = gridDim.x * blockDim.x;
  for (int i = blockIdx.x * blockDim.x + threadIdx.x; i < n4; i += stride) {
    float4 v = ((const float4*)in)[i];
    ushort4 o;
    o.x = f2bf(v.x); o.y = f2bf(v.y); o.z = f2bf(v.z); o.w = f2bf(v.w);
    ((ushort4*)out)[i] = o;
  }
}

// ---------------------------------------------------------------- 8-phase GEMM
// C = A (MxK) * B^T (B given NxK row-major). BK=64, 2 K-tiles/iter, 8 phases.
// 8 waves (2M x 4N), per-wave (BM/2)x(BN/4). LDS: [2 buf][2 khalf][rows][32]
// K-half regions -> 64B LDS rows -> fragment reads naturally conflict-free.
// Counted vmcnt (LA+LB) at phases 4/8 only; stages guarded near K-end (skip
// only -> vmcnt over-drains -> safe). Derivation in round-7 journal.
template <int BM, int BN, typename CT>
__global__ __launch_bounds__(512, 2) void gemm8(const u16* __restrict__ A,
                                                const u16* __restrict__ Bm,
                                                CT* __restrict__ C,
                                                int M, int N, int K) {
  constexpr int PWM = BM / 2, PWN = BN / 4;
  constexpr int MR = PWM / 16, NR = PWN / 16, NB = NR / 2;
  constexpr int LA = BM / 128, LB = BN / 128;  // gload rounds per half-stage
  constexpr int VM = LA + LB;                  // steady-state vmcnt (loads)
  __shared__ u16 sA[4 * BM * 32];
  __shared__ u16 sB[4 * BN * 32];

  const int t = threadIdx.x;
  const int lane = t & 63, wid = t >> 6;
  const int r0 = lane & 15, kq = lane >> 4;
  const int wr = wid >> 2, wc = wid & 3;

  const int nbn = N / BN;
  const int nwg = gridDim.x;                    // must be % 8 == 0
  const int bid = blockIdx.x;
  const int wg = (bid & 7) * (nwg >> 3) + (bid >> 3);  // XCD-chunked, bijective
  const long tile_m = (long)(wg / nbn) * BM;
  const long tile_n = (long)(wg % nbn) * BN;

  const int NT = K >> 6;
  const int NITER = NT >> 1;

  // staging: thread t covers row t/4 (+128*round), 16B slot t&3
  const u16* gA = A + (tile_m + (t >> 2)) * (long)K + (t & 3) * 8;
  const u16* gB = Bm + (tile_n + (t >> 2)) * (long)K + (t & 3) * 8;

  auto stageA = [&](int kt, int kh) {
    u16* base = &sA[((kt & 1) * 2 + kh) * (BM * 32)] + wid * 512;
#pragma unroll
    for (int r = 0; r < LA; ++r)
      gload_lds16(gA + (long)(r * 128) * K + kt * 64 + kh * 32, base + r * 4096);
  };
  auto stageB = [&](int kt, int kh) {
    u16* base = &sB[((kt & 1) * 2 + kh) * (BN * 32)] + wid * 512;
#pragma unroll
    for (int r = 0; r < LB; ++r)
      gload_lds16(gB + (long)(r * 128) * K + kt * 64 + kh * 32, base + r * 4096);
  };

  const int aoff = (wr * PWM + r0) * 32 + kq * 8;
  const int boff = (wc * PWN + r0) * 32 + kq * 8;

  f32x4 acc[MR][NR];
#pragma unroll
  for (int m = 0; m < MR; ++m)
#pragma unroll
    for (int n = 0; n < NR; ++n) acc[m][n] = (f32x4){0.f, 0.f, 0.f, 0.f};

  // prologue: stage ktile0 fully + ktile1 K0-halves; drain ktile0
  stageA(0, 0); stageB(0, 0); stageA(0, 1); stageB(0, 1);
  stageA(1, 0); stageB(1, 0);
  VMCNTN(VM);
  __builtin_amdgcn_s_barrier();

#define PH(KT, KH, G, STAGE_STMT, VM_STMT)                                  \
  {                                                                         \
    const u16* ra = &sA[(((KT) & 1) * 2 + (KH)) * (BM * 32)] + aoff;        \
    const u16* rb = &sB[(((KT) & 1) * 2 + (KH)) * (BN * 32)] + boff;        \
    if ((G) == 0) {                                                         \
      _Pragma("unroll") for (int m = 0; m < MR; ++m)                        \
          a[m] = *(const bf16x8*)(ra + m * 512);                            \
    }                                                                       \
    _Pragma("unroll") for (int n = 0; n < NB; ++n)                          \
        b[n] = *(const bf16x8*)(rb + ((G) * NB + n) * 512);                 \
    STAGE_STMT;                                                             \
    VM_STMT;                                                                \
    __builtin_amdgcn_s_barrier();                                           \
    __builtin_amdgcn_s_setprio(1);                                          \
    _Pragma("unroll") for (int m = 0; m < MR; ++m)                          \
        _Pragma("unroll") for (int n = 0; n < NB; ++n)                      \
            acc[m][(G) * NB + n] = __builtin_amdgcn_mfma_f32_16x16x32_bf16( \
                a[m], b[n], acc[m][(G) * NB + n], 0, 0, 0);                 \
    __builtin_amdgcn_s_setprio(0);                                          \
    __builtin_amdgcn_s_barrier();                                           \
  }

  for (int it = 0; it < NITER; ++it) {
    const int kt0 = 2 * it, kt1 = 2 * it + 1;
    const bool last = (it == NITER - 1);
    bf16x8 a[MR], b[NB];
    PH(kt0, 0, 0, stageA(kt1, 1), ((void)0));
    PH(kt0, 0, 1, stageB(kt1, 1), ((void)0));
    PH(kt0, 1, 0, { if (kt0 + 2 < NT) stageA(kt0 + 2, 0); }, ((void)0));
    PH(kt0, 1, 1, { if (kt0 + 2 < NT) stageB(kt0 + 2, 0); },
       { if (last) { VMCNTN(0); } else { VMCNTN(VM); } });
    PH(kt1, 0, 0, { if (kt0 + 2 < NT) stageA(kt0 + 2, 1); }, ((void)0));
    PH(kt1, 0, 1, { if (kt0 + 2 < NT) stageB(kt0 + 2, 1); }, ((void)0));
    PH(kt1, 1, 0, { if (kt0 + 3 < NT) stageA(kt0 + 3, 0); }, ((void)0));
    PH(kt1, 1, 1, { if (kt0 + 3 < NT) stageB(kt0 + 3, 0); }, VMCNTN(VM));
  }
#undef PH

#pragma unroll
  for (int m = 0; m < MR; ++m)
#pragma unroll
    for (int n = 0; n < NR; ++n)
#pragma unroll
      for (int r = 0; r < 4; ++r) {
        long grow = tile_m + wr * PWM + m * 16 + kq * 4 + r;
        long gcol = tile_n + wc * PWN + n * 16 + r0;
        float v = acc[m][n][r];
        if constexpr (sizeof(CT) == 2) C[grow * N + gcol] = (CT)f2bf(v);
        else                           C[grow * N + gcol] = v;
      }
}

// ---------------------------------------------------------------- RoPE + reshape to (B,H,S,HD)
// q output (z==0) is pre-scaled by 1/sqrt(HD): scaling commutes with rotation.
__global__ void rope_k(const u16* __restrict__ qkv, const float* __restrict__ cosT,
                       const float* __restrict__ sinT, u16* __restrict__ qt,
                       u16* __restrict__ kt) {
  int z = blockIdx.y;
  long idx = (long)blockIdx.x * blockDim.x + threadIdx.x;
  int hd2 = (int)(idx & 63);
  int s   = (int)((idx >> 6) & (S_LEN - 1));
  int bh  = (int)(idx >> 17);
  int b = bh >> 4, h = bh & 15;
  const u16* src = qkv + ((long)(b * S_LEN + s)) * 6144 + z * 2048 + h * HDIM + hd2 * 2;
  ushort2 p = *(const ushort2*)src;
  float e = bf2f(p.x), o = bf2f(p.y);
  float c = cosT[s * 64 + hd2], sn = sinT[s * 64 + hd2];
  float oe = e * c - o * sn;
  float oo = e * sn + o * c;
  if (z == 0) {
    const float sc = 0.08838834764831845f;  // 1/sqrt(128)
    oe *= sc; oo *= sc;
  }
  u16* dst = (z ? kt : qt) + ((long)bh * S_LEN + s) * HDIM + hd2 * 2;
  ushort2 w; w.x = f2bf(oe); w.y = f2bf(oo);
  *(ushort2*)dst = w;
}

// ---------------------------------------------------------------- V transpose -> (B,H,HD,S)
__global__ void vtrans_k(const u16* __restrict__ qkv, u16* __restrict__ vt) {
  __shared__ u16 tile[64][65];
  int bh = blockIdx.z;
  int b = bh >> 4, h = bh & 15;
  int s0 = blockIdx.x * 64, d0 = blockIdx.y * 64;
  int tx = threadIdx.x, ty = threadIdx.y;
#pragma unroll
  for (int i = 0; i < 64; i += 4) {
    int s = s0 + ty + i;
    tile[ty + i][tx] = qkv[((long)(b * S_LEN + s)) * 6144 + 4096 + h * HDIM + d0 + tx];
  }
  __syncthreads();
#pragma unroll
  for (int i = 0; i < 64; i += 4) {
    int d = d0 + ty + i;
    vt[((long)bh * HDIM + d) * S_LEN + s0 + tx] = tile[tx][ty + i];
  }
}

// ---------------------------------------------------------------- flash attention v5 (causal)
__global__ __launch_bounds__(128, 2) void flash_k(const u16* __restrict__ qt,
                                                  const u16* __restrict__ kt,
                                                  const u16* __restrict__ vt,
                                                  u16* __restrict__ attn) {
  constexpr int PS = 40;              // pbuf row stride in u16 (80B, 16B-aligned)
  __shared__ u16 pbuf[2][32 * PS];
  const int t = threadIdx.x, lane = t & 63, wid = t >> 6;
  const int r0 = lane & 15, kq = lane >> 4;
  const int bh = blockIdx.x, b = bh >> 4, h = bh & 15;
  const int tile = (gridDim.y - 1) - blockIdx.y;   // heavy-first
  const int q0w = tile * 64 + wid * 32;            // wave's first q row
  const int crow = kq * 4;                         // C-layout row base

  const u16* qb = qt + ((long)bh * S_LEN + q0w) * HDIM;
  const u16* kb = kt + (long)bh * S_LEN * HDIM;
  const u16* vb = vt + (long)bh * HDIM * S_LEN;
  u16* pb = &pbuf[wid][0];

  bf16x8 aq[2][4];
#pragma unroll
  for (int qc = 0; qc < 2; ++qc)
#pragma unroll
    for (int kk = 0; kk < 4; ++kk)
      aq[qc][kk] = *(const bf16x8*)(qb + (qc * 16 + r0) * HDIM + kk * 32 + kq * 8);

  f32x4 o[2][8];
  float mrow[2] = {-1e30f, -1e30f}, lrow[2] = {0.f, 0.f};
#pragma unroll
  for (int qc = 0; qc < 2; ++qc)
#pragma unroll
    for (int dt = 0; dt < 8; ++dt) o[qc][dt] = (f32x4){0.f, 0.f, 0.f, 0.f};

  bf16x8 bkA[2][4], bkB[2][4];

  auto loadK = [&](bf16x8 (&dst)[2][4], int kv) {
#pragma unroll
    for (int kc = 0; kc < 2; ++kc)
#pragma unroll
      for (int kk = 0; kk < 4; ++kk)
        dst[kc][kk] = *(const bf16x8*)(kb + (long)(kv + kc * 16 + r0) * HDIM + kk * 32 + kq * 8);
  };

  auto step = [&](bf16x8 (&kf)[2][4], bf16x8 (&kfn)[2][4], int kv0) {
    const bool diag = (kv0 == q0w);

    f32x4 sacc[2][2];
    __builtin_amdgcn_s_setprio(1);
#pragma unroll
    for (int kc = 0; kc < 2; ++kc) {
      f32x4 a0 = (f32x4){0.f, 0.f, 0.f, 0.f};
      f32x4 a1 = (f32x4){0.f, 0.f, 0.f, 0.f};
#pragma unroll
      for (int kk = 0; kk < 4; ++kk) {
        a0 = __builtin_amdgcn_mfma_f32_16x16x32_bf16(kf[kc][kk], aq[0][kk], a0, 0, 0, 0);
        a1 = __builtin_amdgcn_mfma_f32_16x16x32_bf16(kf[kc][kk], aq[1][kk], a1, 0, 0, 0);
      }
      sacc[kc][0] = a0; sacc[kc][1] = a1;
    }
    __builtin_amdgcn_s_setprio(0);

    if (kv0 + 32 <= q0w) loadK(kfn, kv0 + 32);

#pragma unroll
    for (int qc = 0; qc < 2; ++qc) {
      float s[2][4];
#pragma unroll
      for (int kc = 0; kc < 2; ++kc)
#pragma unroll
        for (int r = 0; r < 4; ++r) {
          float v = sacc[kc][qc][r];
          if (diag && (kc * 16 + crow + r > qc * 16 + r0)) v = -1e30f;
          s[kc][r] = v;
        }
      float pm = fmaxf(fmaxf(fmaxf(s[0][0], s[0][1]), fmaxf(s[0][2], s[0][3])),
                       fmaxf(fmaxf(s[1][0], s[1][1]), fmaxf(s[1][2], s[1][3])));
      pm = fmaxf(pm, __shfl_xor(pm, 16));
      pm = fmaxf(pm, __shfl_xor(pm, 32));
      if (!__all(pm - mrow[qc] <= 8.0f)) {   // defer-max: rescale rarely
        float mnew = fmaxf(mrow[qc], pm);
        float co = __expf(mrow[qc] - mnew);
        mrow[qc] = mnew;
        lrow[qc] *= co;
        float cod[4];
#pragma unroll
        for (int r = 0; r < 4; ++r)
          cod[r] = __shfl(co, (lane & 48) | (crow + r));
#pragma unroll
        for (int dt = 0; dt < 8; ++dt)
#pragma unroll
          for (int r = 0; r < 4; ++r)
            o[qc][dt][r] *= cod[r];
      }
      float p[2][4];
      float rs = 0.f;
#pragma unroll
      for (int kc = 0; kc < 2; ++kc)
#pragma unroll
        for (int r = 0; r < 4; ++r) {
          p[kc][r] = __expf(s[kc][r] - mrow[qc]);
          rs += p[kc][r];
        }
      rs += __shfl_xor(rs, 16);
      rs += __shfl_xor(rs, 32);
      lrow[qc] += rs;
#pragma unroll
      for (int kc = 0; kc < 2; ++kc) {
        ushort4 pk;
        pk.x = f2bf(p[kc][0]); pk.y = f2bf(p[kc][1]);
        pk.z = f2bf(p[kc][2]); pk.w = f2bf(p[kc][3]);
        *(ushort4*)(pb + (qc * 16 + r0) * PS + kc * 16 + crow) = pk;
      }
    }

    bf16x8 bv[8];
#pragma unroll
    for (int dt = 0; dt < 8; ++dt)
      bv[dt] = *(const bf16x8*)(vb + (long)(dt * 16 + r0) * S_LEN + kv0 + kq * 8);
    bf16x8 pa0 = *(const bf16x8*)(pb + r0 * PS + kq * 8);
    bf16x8 pa1 = *(const bf16x8*)(pb + (16 + r0) * PS + kq * 8);
    __builtin_amdgcn_s_setprio(1);
#pragma unroll
    for (int dt = 0; dt < 8; ++dt) {
      o[0][dt] = __builtin_amdgcn_mfma_f32_16x16x32_bf16(pa0, bv[dt], o[0][dt], 0, 0, 0);
      o[1][dt] = __builtin_amdgcn_mfma_f32_16x16x32_bf16(pa1, bv[dt], o[1][dt], 0, 0, 0);
    }
    __builtin_amdgcn_s_setprio(0);
  };

  loadK(bkA, 0);
  int kv0 = 0;
  for (;;) {
    step(bkA, bkB, kv0); kv0 += 32; if (kv0 > q0w) break;
    step(bkB, bkA, kv0); kv0 += 32; if (kv0 > q0w) break;
  }

#pragma unroll
  for (int qc = 0; qc < 2; ++qc) {
    float linv[4];
#pragma unroll
    for (int r = 0; r < 4; ++r)
      linv[r] = 1.0f / __shfl(lrow[qc], (lane & 48) | (crow + r));
#pragma unroll
    for (int dt = 0; dt < 8; ++dt)
#pragma unroll
      for (int r = 0; r < 4; ++r) {
        int srow = q0w + qc * 16 + crow + r;
        attn[((long)(b * S_LEN + srow)) * DM + h * HDIM + dt * 16 + r0] =
            f2bf(o[qc][dt][r] * linv[r]);
      }
  }
}

// ---------------------------------------------------------------- launch
extern "C" void kernel_launch(void* const* d_in, const int* in_sizes, int n_in,
                              void* d_out, int out_size, void* d_ws, size_t ws_size,
                              hipStream_t stream) {
  (void)in_sizes; (void)n_in; (void)out_size; (void)ws_size;
  const float* x  = (const float*)d_in[0];
  const float* fc = (const float*)d_in[2];
  const float* fs = (const float*)d_in[3];
  const float* wq = (const float*)d_in[5];
  const float* wk = (const float*)d_in[6];
  const float* wv = (const float*)d_in[7];
  const float* wo = (const float*)d_in[8];
  float* out = (float*)d_out;

  u16* xb   = (u16*)d_ws;            // 4096*2048
  u16* wqkv = xb + 8388608;          // 6144*2048
  u16* wob  = wqkv + 12582912;       // 2048*2048
  u16* qkv  = wob + 4194304;         // 4096*6144
  u16* qt   = qkv + 25165824;        // 32*2048*128
  u16* kt   = qt + 8388608;
  u16* vt   = kt + 8388608;
  u16* attn = qkv;                   // alias: qkv dead after rope/vtrans

  cvt_k<<<4096, 256, 0, stream>>>(x, xb, 8388608);
  cvt_k<<<2048, 256, 0, stream>>>(wq, wqkv, 4194304);
  cvt_k<<<2048, 256, 0, stream>>>(wk, wqkv + 4194304, 4194304);
  cvt_k<<<2048, 256, 0, stream>>>(wv, wqkv + 8388608, 4194304);
  cvt_k<<<2048, 256, 0, stream>>>(wo, wob, 4194304);

  // QKV: M=4096 N=6144 K=2048 -> 16x24 = 384 blocks (384%8==0)
  gemm8<256, 256, u16><<<384, 512, 0, stream>>>(xb, wqkv, qkv, 4096, 6144, 2048);

  rope_k<<<dim3(16384, 2), 256, 0, stream>>>(qkv, fc, fs, qt, kt);
  vtrans_k<<<dim3(32, 2, 32), dim3(64, 4), 0, stream>>>(qkv, vt);

  flash_k<<<dim3(32, 32), 128, 0, stream>>>(qt, kt, vt, attn);

  // OUT: M=4096 N=2048 K=2048, BM=128 so grid = 32x8 = 256 blocks (all CUs)
  gemm8<128, 256, float><<<256, 512, 0, stream>>>(attn, wob, out, 4096, 2048, 2048);
}